// Round 4
// baseline (66.127 us; speedup 1.0000x reference)
//
#include <hip/hip_runtime.h>

// TropConv2D: out[b,ho,wo,f] = max_k(patch_k + w[k,f]) - min_k(patch_k + w[k,f])
// x: (8,32,32,32) f32 NHWC, w: (288,64) f32 (72 KB), out: (8,30,30,64) f32
// k = (i*3 + j)*32 + c   (TF extract_patches ordering)
//
// v9: STAGE-FREE. v8 cut LDS issue 2.3x and moved dur <=1us (noise), while
//   v7's regression (+6us) was clearly visible -> LDS/VALU issue BW is NOT
//   the limiter. Remaining in-kernel candidates are serial structure: the
//   global->LDS staging phase + barrier #1 (every wave waits on the slowest
//   of 240 loads, cold from HBM each iteration since the 256MiB workspace
//   fill flushes L2/L3). Fix: x-patch addresses are wave-uniform, and a
//   VMEM load with a uniform address IS a hardware broadcast (one coalesced
//   16B request, L1/L2-cached, reused by 8 waves/block + neighbor blocks).
//   So read x directly from global: no xs[] tile, no staging, no barrier#1.
//   NOT v6/v7's failed scalar path: stays on VMEM pipe, normal per-use
//   s_waitcnt scheduling, VGPR destinations.
//   - register sliding window kept from v8: 30 unique (row,col) vectors,
//     each read once, <=3 taps (px=cc-j) applied immediately. Exact
//     (max/min associative), absmax 0.
//   - weights: rolling 12-per-row prefetch (v5 pattern), issued during
//     previous row's compute.
//   - q=3 clamps cols 32,33 -> 31 (wave-uniform scalar min): stays in
//     bounds (worst row = b7,ho29,r2 = row 255, last of x) and clamped
//     data only feeds px>=6, which the combine discards (npx=6).
//   - only LDS: 32 KB packed {max,min} partials; one barrier total.
//   Discriminator: if dur doesn't move vs v5/v8, the measured quantity is
//   harness floor (41us fill + gap + ~5us kernel) -> roofline.

#define C_IN 32
#define NF 64
#define H_OUT 30
#define W_OUT 30
#define W_IN 32

static __device__ __forceinline__ float max3f(float a, float b, float c) {
    return fmaxf(fmaxf(a, b), c);
}
static __device__ __forceinline__ float min3f(float a, float b, float c) {
    return fminf(fminf(a, b), c);
}

__global__ __launch_bounds__(512) void tropconv_kernel(
    const float* __restrict__ x,
    const float* __restrict__ w,
    float* __restrict__ out) {
    const int bx = blockIdx.x;            // 0..959
    const int q = bx & 3;                 // row quarter
    const int bho = bx >> 2;              // b*30 + ho
    const int b = bho / H_OUT;
    const int ho = bho - b * H_OUT;
    const int tid = threadIdx.x;
    const int lane = tid & 63;            // filter index
    const int wave = tid >> 6;            // channel-slice 0..7 (c = wave*4..+3)

    const int col0 = q * 8;
    const int npx = (q == 3) ? 6 : 8;

    __shared__ __align__(16) float pms[8][8][NF][2];    // 32 KB {max,min} partials

    // wave-uniform x base for this wave's channel slice (VMEM broadcast reads)
    const float* __restrict__ xb =
        x + (size_t)((b * 32 + ho) * W_IN) * C_IN + wave * 4;

    float mx[8], mn[8];
    #pragma unroll
    for (int t = 0; t < 8; ++t) { mx[t] = -INFINITY; mn[t] = INFINITY; }

    // weight lane base: w[(r*3 + j)*32 + wave*4 + cc][lane]
    const float* __restrict__ wlane = w + (size_t)(wave * 4) * NF + lane;

    // prefetch row 0 weights (12: j*4 + cc)
    float wr[12];
    #pragma unroll
    for (int t = 0; t < 12; ++t)
        wr[t] = wlane[((t >> 2) * C_IN + (t & 3)) * NF];

    #pragma unroll 1   // runtime r: bounds live weights at 24, x at 40 VGPRs
    for (int r = 0; r < 3; ++r) {
        // issue this row's 10 uniform-address b128 x loads (compiler pipelines
        // the s_waitcnt per first use; TLP across 20+ waves/CU hides latency)
        float4 xv[10];
        const float* __restrict__ xr = xb + (size_t)r * W_IN * C_IN;
        #pragma unroll
        for (int c = 0; c < 10; ++c) {
            int col = col0 + c;
            col = (col < 31) ? col : 31;   // q==3: cols 32,33 -> 31 (discarded px)
            xv[c] = *(const float4*)(xr + col * C_IN);
        }

        // prefetch next row's weights under this row's compute
        float wn[12];
        if (r < 2) {
            #pragma unroll
            for (int t = 0; t < 12; ++t)
                wn[t] = wlane[(((r + 1) * 3 + (t >> 2)) * C_IN + (t & 3)) * NF];
        }

        // sliding-window taps: each xv[cc] contributes to px = cc - j
        #pragma unroll
        for (int cc = 0; cc < 10; ++cc) {
            const float4 p = xv[cc];
            #pragma unroll
            for (int j = 0; j < 3; ++j) {
                const int px = cc - j;     // compile-time
                if (px >= 0 && px < 8) {
                    float s0 = p.x + wr[j * 4 + 0];
                    float s1 = p.y + wr[j * 4 + 1];
                    float s2 = p.z + wr[j * 4 + 2];
                    float s3 = p.w + wr[j * 4 + 3];
                    mx[px] = max3f(max3f(s0, s1, s2), s3, mx[px]);
                    mn[px] = min3f(min3f(s0, s1, s2), s3, mn[px]);
                }
            }
        }

        if (r < 2) {
            #pragma unroll
            for (int t = 0; t < 12; ++t) wr[t] = wn[t];
        }
    }

    // ---- packed partial store: one b64 per px ----
    #pragma unroll
    for (int px = 0; px < 8; ++px) {
        float2 v; v.x = mx[px]; v.y = mn[px];
        *(float2*)&pms[wave][px][lane][0] = v;
    }
    __syncthreads();

    // ---- cross-wave combine (exact: max/min associative), b128 over f-pairs ----
    if (tid < npx * 32) {
        const int px = tid >> 5;
        const int fp = tid & 31;           // filter pair: f = 2*fp, 2*fp+1
        float4 v0 = *(const float4*)&pms[0][px][fp * 2][0];
        float a0 = v0.x, m0 = v0.y, a1 = v0.z, m1 = v0.w;
        #pragma unroll
        for (int ww = 1; ww < 8; ++ww) {
            const float4 v = *(const float4*)&pms[ww][px][fp * 2][0];
            a0 = fmaxf(a0, v.x); m0 = fminf(m0, v.y);
            a1 = fmaxf(a1, v.z); m1 = fminf(m1, v.w);
        }
        float2 o; o.x = a0 - m0; o.y = a1 - m1;
        *(float2*)&out[((size_t)bho * W_OUT + (col0 + px)) * NF + fp * 2] = o;
    }
}

extern "C" void kernel_launch(void* const* d_in, const int* in_sizes, int n_in,
                              void* d_out, int out_size, void* d_ws, size_t ws_size,
                              hipStream_t stream) {
    const float* x = (const float*)d_in[0];   // 8*32*32*32
    const float* w = (const float*)d_in[1];   // 288*64
    float* out = (float*)d_out;               // 8*30*30*64

    dim3 grid(8 * H_OUT * 4);                 // 960 blocks
    dim3 block(512);
    tropconv_kernel<<<grid, block, 0, stream>>>(x, w, out);
}

// Round 5
// 62.800 us; speedup vs baseline: 1.0530x; 1.0530x over previous
//
#include <hip/hip_runtime.h>

// TropConv2D: out[b,ho,wo,f] = max_k(patch_k + w[k,f]) - min_k(patch_k + w[k,f])
// x: (8,32,32,32) f32 NHWC, w: (288,64) f32 (72 KB), out: (8,30,30,64) f32
// k = (i*3 + j)*32 + c   (TF extract_patches ordering)
//
// v10 = v5 REVERT (best harness-verified: 62.7/63.3 us). Session evidence:
//   five orthogonal structures (LDS-broadcast v5, scalar-SMEM v6/v7,
//   register-slide v8, stage-free-VMEM v9) span only 62.7..68.8 us, and
//   cutting the modeled LDS bottleneck 2.3x (v8) moved nothing while every
//   structural regression (+2..+6 us) was visible. Model: dur ~= 41 us
//   workspace re-poison fill (268 MB @ ~83% HBM, harness-fixed) + ~16 us
//   launch/gap overhead + ~5 us kernel (576 VALU/wave x 7680 waves / 1024
//   SIMDs ~= 3.6 us floor + cold-miss staging). In-kernel headroom is below
//   the noise band -> keep the best-measured configuration.
//
// v5 design (for the record):
//   - 512 thr = 8 waves/block; wave = 4-channel slice (c = wave*4..+3).
//     960 blocks -> 30 waves/CU (~7.5/SIMD, near HW max TLP).
//   - Weight prefetch: ij+1's 4 weights load while ij computes -> L2 latency
//     hidden. Live floats/thread ~45 -> no spill at 64 VGPRs.
//   - Inner body per (ij,px): 1 broadcast ds_read_b128 (imm offsets) +
//     4 add + 2 v_max3 + 2 v_min3. No predicates (q=3 extra px discarded).
//   - Max/min associative -> 8-way channel-split partials exact (absmax 0).

#define C_IN 32
#define NF 64
#define H_OUT 30
#define W_OUT 30
#define W_IN 32

static __device__ __forceinline__ float max3f(float a, float b, float c) {
    return fmaxf(fmaxf(a, b), c);
}
static __device__ __forceinline__ float min3f(float a, float b, float c) {
    return fminf(fminf(a, b), c);
}

__global__ __launch_bounds__(512) void tropconv_kernel(
    const float* __restrict__ x,
    const float* __restrict__ w,
    float* __restrict__ out) {
    const int bx = blockIdx.x;            // 0..959
    const int q = bx & 3;                 // row quarter
    const int bho = bx >> 2;              // b*30 + ho
    const int b = bho / H_OUT;
    const int ho = bho - b * H_OUT;
    const int tid = threadIdx.x;
    const int lane = tid & 63;            // filter index
    const int wave = tid >> 6;            // channel-slice 0..7 (c = wave*4..+3)

    const int col0 = q * 8;
    const int npx = (q == 3) ? 6 : 8;
    const int ncols = (q == 3) ? 8 : 10;  // staged input cols (OOB-safe for q=3)

    __shared__ __align__(16) float xs[3 * 10 * C_IN];  // 3.75 KB patch tile
    __shared__ float pmx[8][8][NF];                    // 16 KB partial max
    __shared__ float pmn[8][8][NF];                    // 16 KB partial min

    // ---- Stage patch rows (contiguous NHWC segments, coalesced float4) ----
    {
        const int nf4_row = ncols * (C_IN / 4);    // 80 or 64 float4 per row
        const int total_f4 = 3 * nf4_row;          // 240 or 192 (< 512)
        if (tid < total_f4) {
            const int r = tid / nf4_row;
            const int cc = tid - r * nf4_row;
            const float4* __restrict__ src = (const float4*)(
                x + ((size_t)((b * 32 + ho + r) * W_IN + col0)) * C_IN);
            ((float4*)xs)[r * 80 + cc] = src[cc];
        }
    }

    // Weight base for this wave's channel slice: w[(ij*32 + wave*4 + cc)*64 + lane]
    const float* __restrict__ wbase = w + (size_t)(wave * 4) * NF + lane;

    float wc[4];                           // current ij weights (prefetched)
    #pragma unroll
    for (int cc = 0; cc < 4; ++cc) wc[cc] = wbase[cc * NF];

    __syncthreads();

    float mx[8], mn[8];
    #pragma unroll
    for (int t = 0; t < 8; ++t) { mx[t] = -INFINITY; mn[t] = INFINITY; }

    #pragma unroll
    for (int ij = 0; ij < 9; ++ij) {
        // prefetch next ij's weights (hidden behind this ij's compute)
        float wn[4];
        if (ij < 8) {
            #pragma unroll
            for (int cc = 0; cc < 4; ++cc)
                wn[cc] = wbase[((ij + 1) * C_IN + cc) * NF];
        }

        const int i = ij / 3;
        const int j = ij - i * 3;
        // single vaddr per ij; px becomes an immediate offset (px*128 B)
        const float* __restrict__ xrow = xs + (i * 10 + j) * C_IN + wave * 4;

        #pragma unroll
        for (int px = 0; px < 8; ++px) {   // q=3: px>=6 reads uninit LDS, discarded
            float4 p = *(const float4*)(xrow + px * C_IN);  // broadcast b128
            float s0 = p.x + wc[0];
            float s1 = p.y + wc[1];
            float s2 = p.z + wc[2];
            float s3 = p.w + wc[3];
            mx[px] = max3f(max3f(s0, s1, s2), s3, mx[px]);
            mn[px] = min3f(min3f(s0, s1, s2), s3, mn[px]);
        }

        #pragma unroll
        for (int cc = 0; cc < 4; ++cc) wc[cc] = wn[cc];
    }

    #pragma unroll
    for (int px = 0; px < 8; ++px) {
        pmx[wave][px][lane] = mx[px];
        pmn[wave][px][lane] = mn[px];
    }
    __syncthreads();

    // ---- Cross-wave combine (exact: max/min associative) ----
    const int nout = npx * NF;            // 512 or 384
    if (tid < nout) {
        const int px = tid >> 6;
        const int f = tid & 63;
        float a = fmaxf(fmaxf(fmaxf(pmx[0][px][f], pmx[1][px][f]),
                              fmaxf(pmx[2][px][f], pmx[3][px][f])),
                        fmaxf(fmaxf(pmx[4][px][f], pmx[5][px][f]),
                              fmaxf(pmx[6][px][f], pmx[7][px][f])));
        float m = fminf(fminf(fminf(pmn[0][px][f], pmn[1][px][f]),
                              fminf(pmn[2][px][f], pmn[3][px][f])),
                        fminf(fminf(pmn[4][px][f], pmn[5][px][f]),
                              fminf(pmn[6][px][f], pmn[7][px][f])));
        out[((size_t)bho * W_OUT + (col0 + px)) * NF + f] = a - m;
    }
}

extern "C" void kernel_launch(void* const* d_in, const int* in_sizes, int n_in,
                              void* d_out, int out_size, void* d_ws, size_t ws_size,
                              hipStream_t stream) {
    const float* x = (const float*)d_in[0];   // 8*32*32*32
    const float* w = (const float*)d_in[1];   // 288*64
    float* out = (float*)d_out;               // 8*30*30*64

    dim3 grid(8 * H_OUT * 4);                 // 960 blocks
    dim3 block(512);
    tropconv_kernel<<<grid, block, 0, stream>>>(x, w, out);
}